// Round 1
// baseline (70.528 us; speedup 1.0000x reference)
//
#include <hip/hip_runtime.h>

#define N 4096

__device__ __forceinline__ int pad(int p) { return p + (p >> 4); }

__global__ __launch_bounds__(256, 4) void butterfly_kernel(
    const float* __restrict__ x,
    const float* __restrict__ w0, const float* __restrict__ w1, const float* __restrict__ w2,
    const float* __restrict__ l0, const float* __restrict__ l1, const float* __restrict__ l2,
    float* __restrict__ out)
{
    __shared__ float lds[N + (N >> 4)];   // padded: addr(p) = p + (p>>4); 17408 B
    const int t = threadIdx.x;
    const int row = blockIdx.x;
    const float* __restrict__ xr = x + (size_t)row * N;
    float* __restrict__ orow = out + (size_t)row * N;

    // ---- load 16 contiguous elements (4 x float4) ----
    float v[16];
    const float4* xq = (const float4*)(xr + t * 16);
    #pragma unroll
    for (int q = 0; q < 4; ++q) {
        float4 f = xq[q];
        v[q*4+0] = f.x; v[q*4+1] = f.y; v[q*4+2] = f.z; v[q*4+3] = f.w;
    }

    // ---- level 2 (stride-1 mix, thread-local): r2[i] = sum_j l2[i][j]*w2[j]*x[j] + x[i] ----
    float xw[16];
    #pragma unroll
    for (int j = 0; j < 16; ++j) xw[j] = w2[j] * v[j];       // w2 uniform -> SGPR
    float r2[16];
    #pragma unroll
    for (int i = 0; i < 16; ++i) {
        float acc = v[i];                                     // residual (level-2 input = x)
        #pragma unroll
        for (int j = 0; j < 16; ++j) acc = fmaf(l2[i*16+j], xw[j], acc);  // l2 uniform -> SGPR
        r2[i] = acc;
    }

    // ---- transpose via LDS: natural layout p = t*16+k ----
    #pragma unroll
    for (int k = 0; k < 16; ++k) lds[pad(t*16+k)] = r2[k];
    __syncthreads();

    // ---- level 1 (stride-16 mix within 256-blocks), owner (b1 = t>>4, c1 = t&15) ----
    const int b1 = t >> 4, c1 = t & 15;
    float y1[16];
    #pragma unroll
    for (int j = 0; j < 16; ++j)
        y1[j] = w1[j*16 + c1] * lds[pad(b1*256 + j*16 + c1)];
    float r1[16];
    #pragma unroll
    for (int i = 0; i < 16; ++i) {
        float acc = 0.f;                                      // no residual at level 1
        #pragma unroll
        for (int j = 0; j < 16; ++j) acc = fmaf(l1[i*16+j], y1[j], acc);
        r1[i] = acc;
    }

    __syncthreads();   // everyone done reading r2 from lds
    #pragma unroll
    for (int i = 0; i < 16; ++i) lds[pad(b1*256 + i*16 + c1)] = r1[i];
    __syncthreads();

    // ---- level 0 (stride-256 mix), owner c0 = t ----
    float y0[16];
    #pragma unroll
    for (int j = 0; j < 16; ++j)
        y0[j] = w0[j*256 + t] * lds[pad(j*256 + t)];          // w0 coalesced, L2-hot
    #pragma unroll
    for (int i = 0; i < 16; ++i) {
        float acc = 0.f;
        #pragma unroll
        for (int j = 0; j < 16; ++j) acc = fmaf(l0[i*16+j], y0[j], acc);
        orow[i*256 + t] = acc + xr[i*256 + t];                // residual = original x (L1/L2-hot)
    }
}

extern "C" void kernel_launch(void* const* d_in, const int* in_sizes, int n_in,
                              void* d_out, int out_size, void* d_ws, size_t ws_size,
                              hipStream_t stream) {
    const float* x  = (const float*)d_in[0];
    const float* w0 = (const float*)d_in[1];
    const float* w1 = (const float*)d_in[2];
    const float* w2 = (const float*)d_in[3];
    const float* l0 = (const float*)d_in[4];
    const float* l1 = (const float*)d_in[5];
    const float* l2 = (const float*)d_in[6];
    float* out = (float*)d_out;
    const int rows = in_sizes[0] / N;
    butterfly_kernel<<<rows, 256, 0, stream>>>(x, w0, w1, w2, l0, l1, l2, out);
}

// Round 2
// 66.035 us; speedup vs baseline: 1.0680x; 1.0680x over previous
//
#include <hip/hip_runtime.h>

#define N 4096
// padded float2 layout: logical float-index p -> slot p + (p>>4), stride 16 -> 17
// T1 write: t*17 + k ; T1 read: b1*272 + j*17 + c1 ; T2 write: b1*272 + i*17 + c1
// T2 read: j*272 + t + (t>>4)   (272 = 16*17) — all affine in the loop var -> imm offsets

__global__ __launch_bounds__(256, 4) void butterfly2_kernel(
    const float* __restrict__ x,
    const float* __restrict__ w0, const float* __restrict__ w1, const float* __restrict__ w2,
    const float* __restrict__ l0, const float* __restrict__ l1, const float* __restrict__ l2,
    float* __restrict__ out)
{
    __shared__ float2 lds[N + (N >> 4)];   // 4352 float2 = 34816 B
    const int t = threadIdx.x;
    const int b1 = t >> 4, c1 = t & 15;
    const size_t row0 = (size_t)blockIdx.x * 2;
    const float* __restrict__ xA = x + row0 * N;
    const float* __restrict__ xB = xA + N;
    float* __restrict__ oA = out + row0 * N;
    float* __restrict__ oB = oA + N;

    // ---- load 16 contiguous elements for each of the two rows ----
    float vA[16], vB[16];
    {
        const float4* qA = (const float4*)(xA + t * 16);
        const float4* qB = (const float4*)(xB + t * 16);
        float4 fa0 = qA[0], fa1 = qA[1], fa2 = qA[2], fa3 = qA[3];
        float4 fb0 = qB[0], fb1 = qB[1], fb2 = qB[2], fb3 = qB[3];
        vA[0]=fa0.x; vA[1]=fa0.y; vA[2]=fa0.z; vA[3]=fa0.w;
        vA[4]=fa1.x; vA[5]=fa1.y; vA[6]=fa1.z; vA[7]=fa1.w;
        vA[8]=fa2.x; vA[9]=fa2.y; vA[10]=fa2.z; vA[11]=fa2.w;
        vA[12]=fa3.x; vA[13]=fa3.y; vA[14]=fa3.z; vA[15]=fa3.w;
        vB[0]=fb0.x; vB[1]=fb0.y; vB[2]=fb0.z; vB[3]=fb0.w;
        vB[4]=fb1.x; vB[5]=fb1.y; vB[6]=fb1.z; vB[7]=fb1.w;
        vB[8]=fb2.x; vB[9]=fb2.y; vB[10]=fb2.z; vB[11]=fb2.w;
        vB[12]=fb3.x; vB[13]=fb3.y; vB[14]=fb3.z; vB[15]=fb3.w;
    }

    // ---- level 2 (thread-local 16x16 matvec, residual = x) ----
    float xwA[16], xwB[16];
    #pragma unroll
    for (int j = 0; j < 16; ++j) {
        float s = w2[j];                 // uniform -> SGPR
        xwA[j] = s * vA[j];
        xwB[j] = s * vB[j];
    }
    #pragma unroll
    for (int i = 0; i < 16; ++i) {
        float a = vA[i], b = vB[i];      // residual (level-2 res flag = True)
        #pragma unroll
        for (int j = 0; j < 16; ++j) {
            float s = l2[i*16 + j];      // uniform -> SGPR
            a = fmaf(s, xwA[j], a);
            b = fmaf(s, xwB[j], b);
        }
        lds[t*17 + i] = make_float2(a, b);   // paired b64 write
    }

    // hoist w1 column (reused by both rows); latency hides under the barrier
    float w1c[16];
    #pragma unroll
    for (int j = 0; j < 16; ++j) w1c[j] = w1[j*16 + c1];

    __syncthreads();

    // ---- level 1 (stride-16 mix, no residual) ----
    float2 y1[16];
    #pragma unroll
    for (int j = 0; j < 16; ++j) {
        float2 p = lds[b1*272 + j*17 + c1];  // paired b64 read
        y1[j].x = w1c[j] * p.x;
        y1[j].y = w1c[j] * p.y;
    }
    float r1A[16], r1B[16];
    #pragma unroll
    for (int i = 0; i < 16; ++i) {
        float a = 0.f, b = 0.f;
        #pragma unroll
        for (int j = 0; j < 16; ++j) {
            float s = l1[i*16 + j];
            a = fmaf(s, y1[j].x, a);
            b = fmaf(s, y1[j].y, b);
        }
        r1A[i] = a; r1B[i] = b;
    }

    __syncthreads();
    #pragma unroll
    for (int i = 0; i < 16; ++i)
        lds[b1*272 + i*17 + c1] = make_float2(r1A[i], r1B[i]);

    // hoist w0 column + residual x (used after the barrier; latency hidden)
    float w0c[16], xrA[16], xrB[16];
    #pragma unroll
    for (int j = 0; j < 16; ++j) w0c[j] = w0[j*256 + t];
    #pragma unroll
    for (int i = 0; i < 16; ++i) { xrA[i] = xA[i*256 + t]; xrB[i] = xB[i*256 + t]; }

    __syncthreads();

    // ---- level 0 (stride-256 mix, residual = original x) ----
    const int tb = t + (t >> 4);
    float2 y0[16];
    #pragma unroll
    for (int j = 0; j < 16; ++j) {
        float2 p = lds[j*272 + tb];          // paired b64 read
        y0[j].x = w0c[j] * p.x;
        y0[j].y = w0c[j] * p.y;
    }
    #pragma unroll
    for (int i = 0; i < 16; ++i) {
        float a = xrA[i], b = xrB[i];
        #pragma unroll
        for (int j = 0; j < 16; ++j) {
            float s = l0[i*16 + j];
            a = fmaf(s, y0[j].x, a);
            b = fmaf(s, y0[j].y, b);
        }
        oA[i*256 + t] = a;
        oB[i*256 + t] = b;
    }
}

extern "C" void kernel_launch(void* const* d_in, const int* in_sizes, int n_in,
                              void* d_out, int out_size, void* d_ws, size_t ws_size,
                              hipStream_t stream) {
    const float* x  = (const float*)d_in[0];
    const float* w0 = (const float*)d_in[1];
    const float* w1 = (const float*)d_in[2];
    const float* w2 = (const float*)d_in[3];
    const float* l0 = (const float*)d_in[4];
    const float* l1 = (const float*)d_in[5];
    const float* l2 = (const float*)d_in[6];
    float* out = (float*)d_out;
    const int rows = in_sizes[0] / N;
    butterfly2_kernel<<<rows / 2, 256, 0, stream>>>(x, w0, w1, w2, l0, l1, l2, out);
}